// Round 2
// baseline (2821.384 us; speedup 1.0000x reference)
//
#include <hip/hip_runtime.h>

// Neural SDE rollout, split-K across blocks. R2: exchange mechanism swap.
// Geometry is R0's validated config (64 groups x 16 rows, 8 blocks/group
// owning a 64-col H-slice, 512 blocks x 512 thr, 2 blocks/CU, VGPR<=128).
// R1 post-mortem: register-resident weights failed (compiler capped at 128
// VGPR, spilled -> WRITE_SIZE 2x) and 1 block/CU lost cross-block latency
// hiding. R2 theory: the R0 residual (~13 us/step over compute+stream) is
// device-atomic THROUGHPUT -- 512K 4B atomicAdd RMWs/step serialized at the
// memory-side coherence point. Replace with per-block slot STORES (plain,
// line-coalesced, fire-and-forget) + release counter + 8-slot readback sum
// in VALU. RMW count/step: 512K -> 512 (counter incs only). Parity-2 slot
// rotation removes the zeroing pass entirely.

typedef _Float16 f16x8 __attribute__((ext_vector_type(8)));
typedef float    f32x4 __attribute__((ext_vector_type(4)));

#define MFMA(a,b,c) __builtin_amdgcn_mfma_f32_16x16x32_f16(a,b,c,0,0,0)

#define Bb 1024
#define Tt 128
#define NG 64          // groups
#define GB 8           // blocks per group (split-K over H=512 -> 64 cols each)
#define Rr 16          // rows per group (one MFMA M-tile)
#define NT 512         // threads per block (8 waves)

// packed fragment regions in d_ws (units: halves) -- identical pack to R0
#define W2SG_OFF 0
#define W2SG_HALVES (64*16*2*512)
#define W2MU_OFF (W2SG_OFF + W2SG_HALVES)
#define W2MU_HALVES (4*16*2*512)
#define W1MU_OFF (W2MU_OFF + W2MU_HALVES)
#define W1_HALVES (32*3*2*512)
#define W1SG_OFF (W1MU_OFF + W1_HALVES)
#define WS_HALVES (W1SG_OFF + W1_HALVES)
#define ACC_BYTES_OFF ((size_t)WS_HALVES * 2)
#define ACC_FLOATS (2 * NG * GB * 1024)   // 2 parity slots x 64 grp x 8 blk x 1024
#define CNT_BYTES_OFF (ACC_BYTES_OFF + (size_t)ACC_FLOATS * 4)
#define CNT_STRIDE 16                     // pad counters to 64 B

__global__ __launch_bounds__(256) void pack_weights(
    const float* __restrict__ W1_mu, const float* __restrict__ W2_mu,
    const float* __restrict__ W1_sg, const float* __restrict__ W2_sg,
    _Float16* __restrict__ wsh)
{
    int gid = blockIdx.x * 256 + threadIdx.x;
    if (gid >= 81920) return;
    const float* src; int ncols, kvalid; size_t dst;
    int id, tile, ks, lane;
    if (gid < 65536) {                 // W2_sg: 64 tiles x 16 ks x 64 lanes
        id = gid; tile = id >> 10; id &= 1023; ks = id >> 6; lane = id & 63;
        src = W2_sg; ncols = 1024; kvalid = 512;
        dst = W2SG_OFF + (size_t)((tile*16 + ks)*2) * 512 + lane*8;
    } else if (gid < 69632) {          // W2_mu: 4 x 16 x 64
        id = gid - 65536; tile = id >> 10; id &= 1023; ks = id >> 6; lane = id & 63;
        src = W2_mu; ncols = 64; kvalid = 512;
        dst = W2MU_OFF + (size_t)((tile*16 + ks)*2) * 512 + lane*8;
    } else if (gid < 75776) {          // W1_mu: 32 tiles x 3 ks x 64
        id = gid - 69632; tile = id / 192; id %= 192; ks = id >> 6; lane = id & 63;
        src = W1_mu; ncols = 512; kvalid = 80;
        dst = W1MU_OFF + (size_t)((tile*3 + ks)*2) * 512 + lane*8;
    } else {                           // W1_sg
        id = gid - 75776; tile = id / 192; id %= 192; ks = id >> 6; lane = id & 63;
        src = W1_sg; ncols = 512; kvalid = 80;
        dst = W1SG_OFF + (size_t)((tile*3 + ks)*2) * 512 + lane*8;
    }
    const int n  = tile*16 + (lane & 15);
    const int kb = ks*32 + ((lane >> 4) << 3);
    f16x8 hi8, lo8;
    #pragma unroll
    for (int jj = 0; jj < 8; ++jj) {
        int k = kb + jj;
        float wv = (k < kvalid) ? src[(size_t)k * ncols + n] : 0.f;
        _Float16 h = (_Float16)wv;
        hi8[jj] = h;
        lo8[jj] = (_Float16)(wv - (float)h);
    }
    *((f16x8*)(wsh + dst))       = hi8;
    *((f16x8*)(wsh + dst + 512)) = lo8;
}

__global__ __launch_bounds__(NT, 4) void nsde_store(
    const float* __restrict__ y0, const float* __restrict__ controls,
    const float* __restrict__ noise,
    const float* __restrict__ b1_mu, const float* __restrict__ b2_mu,
    const float* __restrict__ b1_sg, const float* __restrict__ b2_sg,
    const _Float16* __restrict__ wf,
    float* __restrict__ accbuf, unsigned int* __restrict__ cnt,
    float* __restrict__ out)
{
    __shared__ _Float16 s_xhi[Rr][104], s_xlo[Rr][104];     // x, K=96 (+pad)
    __shared__ _Float16 s_hhi[2][Rr][72], s_hlo[2][Rr][72]; // h slices (64+pad)
    __shared__ float s_y[Rr*64];     // [r*64+n]
    __shared__ float s_dw[Rr][16];
    __shared__ float s_part[Rr*64];  // sg partial (dW-folded)
    __shared__ float s_pmu[Rr*64];   // mu partial (*dt)

    const int tid  = threadIdx.x;
    const int lane = tid & 63, w = tid >> 6;
    const int m15  = lane & 15, quad = lane >> 4;
    const int j    = blockIdx.x & 7;        // K-slice id
    const int g    = blockIdx.x >> 3;       // group
    const int r0   = g * Rr;

    // per-wave constants
    const int l  = w >> 2;                  // GEMM1 layer: 0=mu 1=sg
    const int ct = w & 3;                   // GEMM1 col-tile within slice
    const int tg = j*4 + ct;                // global W1 H-tile
    const _Float16* w1base = wf + (l ? W1SG_OFF : W1MU_OFF);
    const float bias1 = (l ? b1_sg : b1_mu)[j*64 + ct*16 + m15];
    float b2v[8];
    #pragma unroll
    for (int t = 0; t < 8; ++t)
        b2v[t] = (j == 0) ? b2_sg[(w + t*8)*16 + m15] : 0.f;
    const float b2m = (w < 4 && j == 0) ? b2_mu[w*16 + m15] * 0.01f : 0.f;

    // ---- init
    for (int e = tid; e < Rr*24; e += NT) {   // zero x K-pad cols 80..103
        int r = e / 24, c = 80 + e % 24;
        s_xhi[r][c] = (_Float16)0.f; s_xlo[r][c] = (_Float16)0.f;
    }
    if (tid < 256) {
        int e0 = tid*4, r = e0 >> 6, n = e0 & 63;
        float4 yv = *(const float4*)&y0[(size_t)(r0 + r)*64 + n];
        float vv[4] = {yv.x, yv.y, yv.z, yv.w};
        #pragma unroll
        for (int q = 0; q < 4; ++q) {
            s_y[e0+q] = vv[q];
            _Float16 h = (_Float16)vv[q];
            s_xhi[r][n+q] = h; s_xlo[r][n+q] = (_Float16)(vv[q] - (float)h);
        }
        if ((tid >> 5) == j)
            *(float4*)&out[(size_t)(r0 + r)*64 + n] = yv;
        int rr2 = tid >> 4, cc2 = tid & 15;
        float u = controls[cc2];
        _Float16 h = (_Float16)u;
        s_xhi[rr2][64+cc2] = h; s_xlo[rr2][64+cc2] = (_Float16)(u - (float)h);
        s_dw[rr2][cc2] = noise[(size_t)(r0 + rr2)*16 + cc2] * 0.1f;
    }
    __syncthreads();

    for (int k = 0; k < Tt-1; ++k) {
        // ======== GEMM1: one 16-col tile per wave, both layers in parallel
        {
            f32x4 a0 = {0,0,0,0}, a1 = {0,0,0,0}, a2 = {0,0,0,0};
            #pragma unroll
            for (int ks = 0; ks < 3; ++ks) {
                const _Float16* bp = w1base + (size_t)((tg*3 + ks)*2)*512 + lane*8;
                f16x8 bh = *(const f16x8*)bp;
                f16x8 bl = *(const f16x8*)(bp + 512);
                f16x8 ah = *(const f16x8*)&s_xhi[m15][ks*32 + quad*8];
                f16x8 al = *(const f16x8*)&s_xlo[m15][ks*32 + quad*8];
                a0 = MFMA(ah, bh, a0);
                a1 = MFMA(ah, bl, a1);
                a2 = MFMA(al, bh, a2);
            }
            f32x4 s = a0 + a1 + a2;
            #pragma unroll
            for (int rg = 0; rg < 4; ++rg) {
                int row = quad*4 + rg;
                float v = fmaxf(s[rg] + bias1, 0.f);
                _Float16 h = (_Float16)v;
                s_hhi[l][row][ct*16 + m15] = h;
                s_hlo[l][row][ct*16 + m15] = (_Float16)(v - (float)h);
            }
        }
        // prefetch next-step controls/noise into regs (hidden under GEMM2)
        float u_nx = 0.f, dw_nx = 0.f;
        const int r2 = tid >> 4, c2 = tid & 15;
        if (k < Tt-2 && tid < 256) {
            u_nx  = controls[(size_t)(k+1)*16 + c2];
            dw_nx = noise[((size_t)(k+1)*Bb + r0 + r2)*16 + c2] * 0.1f;
        }
        __syncthreads();

        // ======== GEMM2 over this block's K-slice (local k in [0,64))
        float dwv[4];
        #pragma unroll
        for (int rg = 0; rg < 4; ++rg)
            dwv[rg] = s_dw[quad*4 + rg][m15];

        // -- mu partial (waves 0..3 take n-tile w)
        if (w < 4) {
            f16x8 Mh0 = *(const f16x8*)&s_hhi[0][m15][quad*8];
            f16x8 Ml0 = *(const f16x8*)&s_hlo[0][m15][quad*8];
            f16x8 Mh1 = *(const f16x8*)&s_hhi[0][m15][32 + quad*8];
            f16x8 Ml1 = *(const f16x8*)&s_hlo[0][m15][32 + quad*8];
            const _Float16* bp = wf + W2MU_OFF + (size_t)((w*16 + 2*j)*2)*512 + lane*8;
            f16x8 bh0 = *(const f16x8*)(bp);
            f16x8 bl0 = *(const f16x8*)(bp + 512);
            f16x8 bh1 = *(const f16x8*)(bp + 1024);
            f16x8 bl1 = *(const f16x8*)(bp + 1536);
            f32x4 hh = {0,0,0,0}, hl = {0,0,0,0}, lh = {0,0,0,0};
            hh = MFMA(Mh0, bh0, hh); hl = MFMA(Mh0, bl0, hl); lh = MFMA(Ml0, bh0, lh);
            hh = MFMA(Mh1, bh1, hh); hl = MFMA(Mh1, bl1, hl); lh = MFMA(Ml1, bh1, lh);
            f32x4 s = hh + hl + lh;
            #pragma unroll
            for (int rg = 0; rg < 4; ++rg)
                s_pmu[(quad*4 + rg)*64 + w*16 + m15] = s[rg]*0.01f + b2m;
        }

        // -- sg partials: 8 n-tiles per wave
        f16x8 Ah0 = *(const f16x8*)&s_hhi[1][m15][quad*8];
        f16x8 Al0 = *(const f16x8*)&s_hlo[1][m15][quad*8];
        f16x8 Ah1 = *(const f16x8*)&s_hhi[1][m15][32 + quad*8];
        f16x8 Al1 = *(const f16x8*)&s_hlo[1][m15][32 + quad*8];
        #pragma unroll 2
        for (int t = 0; t < 8; ++t) {
            const int nt = w + t*8;
            const _Float16* bp = wf + W2SG_OFF + (size_t)((nt*16 + 2*j)*2)*512 + lane*8;
            f16x8 bh0 = *(const f16x8*)(bp);
            f16x8 bl0 = *(const f16x8*)(bp + 512);
            f16x8 bh1 = *(const f16x8*)(bp + 1024);
            f16x8 bl1 = *(const f16x8*)(bp + 1536);
            f32x4 hh = {0,0,0,0}, hl = {0,0,0,0}, lh = {0,0,0,0};
            hh = MFMA(Ah0, bh0, hh); hl = MFMA(Ah0, bl0, hl); lh = MFMA(Al0, bh0, lh);
            hh = MFMA(Ah1, bh1, hh); hl = MFMA(Ah1, bl1, hl); lh = MFMA(Al1, bh1, lh);
            f32x4 s = hh + hl + lh;
            #pragma unroll
            for (int rg = 0; rg < 4; ++rg) {
                float v = (s[rg] + b2v[t]) * dwv[rg];
                v += __shfl_xor(v, 1); v += __shfl_xor(v, 2);
                v += __shfl_xor(v, 4); v += __shfl_xor(v, 8);
                if (m15 == 0) s_part[(quad*4 + rg)*64 + nt] = v;
            }
        }
        __syncthreads();

        // ======== exchange: plain stores to own sub-slot (parity buffered)
        const int slot = k & 1;
        float* ab = accbuf + (((size_t)slot*NG + g)*GB + j)*1024;
        const int e0 = tid*2;
        {
            float v0 = s_part[e0]   + s_pmu[e0];
            float v1 = s_part[e0+1] + s_pmu[e0+1];
            __hip_atomic_store(&ab[e0],   v0, __ATOMIC_RELAXED,
                               __HIP_MEMORY_SCOPE_AGENT);
            __hip_atomic_store(&ab[e0+1], v1, __ATOMIC_RELAXED,
                               __HIP_MEMORY_SCOPE_AGENT);
        }
        __syncthreads();   // drains vmcnt: all stores at coherence point
        if (tid == 0) {
            __hip_atomic_fetch_add(&cnt[g*CNT_STRIDE], 1u, __ATOMIC_RELEASE,
                                   __HIP_MEMORY_SCOPE_AGENT);
            while (__hip_atomic_load(&cnt[g*CNT_STRIDE], __ATOMIC_RELAXED,
                                     __HIP_MEMORY_SCOPE_AGENT) < (unsigned)GB*(k+1))
                __builtin_amdgcn_s_sleep(2);
        }
        __syncthreads();

        // ======== read 8 sub-slots, sum in VALU, y update, out write
        {
            const int r = e0 >> 6, n = e0 & 63;
            const float* rb = accbuf + (((size_t)slot*NG + g)*GB)*1024;
            float a0[GB], a1[GB];
            #pragma unroll
            for (int b = 0; b < GB; ++b) {
                a0[b] = __hip_atomic_load(&rb[(size_t)b*1024 + e0],
                                          __ATOMIC_RELAXED, __HIP_MEMORY_SCOPE_AGENT);
                a1[b] = __hip_atomic_load(&rb[(size_t)b*1024 + e0 + 1],
                                          __ATOMIC_RELAXED, __HIP_MEMORY_SCOPE_AGENT);
            }
            float sum0 = ((a0[0]+a0[1])+(a0[2]+a0[3]))+((a0[4]+a0[5])+(a0[6]+a0[7]));
            float sum1 = ((a1[0]+a1[1])+(a1[2]+a1[3]))+((a1[4]+a1[5])+(a1[6]+a1[7]));
            float ya = s_y[e0]   + sum0;
            float yb = s_y[e0+1] + sum1;
            s_y[e0] = ya; s_y[e0+1] = yb;
            _Float16 ha = (_Float16)ya, hb = (_Float16)yb;
            s_xhi[r][n] = ha;   s_xlo[r][n]   = (_Float16)(ya - (float)ha);
            s_xhi[r][n+1] = hb; s_xlo[r][n+1] = (_Float16)(yb - (float)hb);
            if ((tid >> 6) == j) {   // wave j writes this block's 128-elem chunk
                float2 o = {ya, yb};
                *(float2*)&out[((size_t)(k+1)*Bb + r0 + r)*64 + n] = o;
            }
        }
        if (k < Tt-2 && tid < 256) {
            _Float16 h = (_Float16)u_nx;
            s_xhi[r2][64+c2] = h; s_xlo[r2][64+c2] = (_Float16)(u_nx - (float)h);
            s_dw[r2][c2] = dw_nx;
        }
        __syncthreads();
    }
}

extern "C" void kernel_launch(void* const* d_in, const int* in_sizes, int n_in,
                              void* d_out, int out_size, void* d_ws, size_t ws_size,
                              hipStream_t stream) {
    const float* y0       = (const float*)d_in[0];
    const float* controls = (const float*)d_in[1];
    const float* noise    = (const float*)d_in[2];
    const float* W1_mu    = (const float*)d_in[3];
    const float* b1_mu    = (const float*)d_in[4];
    const float* W2_mu    = (const float*)d_in[5];
    const float* b2_mu    = (const float*)d_in[6];
    const float* W1_sg    = (const float*)d_in[7];
    const float* b1_sg    = (const float*)d_in[8];
    const float* W2_sg    = (const float*)d_in[9];
    const float* b2_sg    = (const float*)d_in[10];
    float* out = (float*)d_out;
    _Float16* wsh = (_Float16*)d_ws;
    float* accbuf = (float*)((char*)d_ws + ACC_BYTES_OFF);
    unsigned int* cnt = (unsigned int*)((char*)d_ws + CNT_BYTES_OFF);

    // zero only the release counters (slots are write-before-read now;
    // ws is poisoned 0xAA each call)
    hipMemsetAsync((char*)d_ws + CNT_BYTES_OFF, 0,
                   (size_t)NG*CNT_STRIDE*4, stream);
    pack_weights<<<320, 256, 0, stream>>>(W1_mu, W2_mu, W1_sg, W2_sg, wsh);
    nsde_store<<<NG*GB, NT, 0, stream>>>(y0, controls, noise,
                                         b1_mu, b2_mu, b1_sg, b2_sg,
                                         (const _Float16*)wsh,
                                         accbuf, cnt, out);
}

// Round 3
// 2777.851 us; speedup vs baseline: 1.0157x; 1.0157x over previous
//
#include <hip/hip_runtime.h>

// Neural SDE rollout, split-K across blocks. R3: weight-reuse geometry.
// R2 post-mortem: store+readback exchange was NOT faster than atomicAdd ->
// exchange mechanism is not the bottleneck. Arithmetic says R0 was L2-BW
// bound on weight streaming: 320 KB/block/step x 512 blocks = 164 MB/step
// = 34.5 TB/s (the measured L2 ceiling) for ~4.7 us of each 18 us step.
// R3: NG=32 groups x Rr=32 rows (2 M-tiles), GB=8 -> 256 blocks, 1/CU.
// Each streamed weight fragment now feeds 2 M-tiles -> weight traffic
// halves (320 KB/CU/step); groups own 8 dedicated CUs -> no cross-group
// jitter coupling. Exchange = R0/R1's validated 3-slot atomicAdd + release
// counter, verbatim. vs R1 (which spilled): W2_sg weights are STREAMED --
// an opaque-zero asm offset defeats LICM so the compiler cannot pin
// 128 VGPRs of sg weights across the T-loop. W1/W2_mu (40 VGPRs) stay
// register-resident on purpose.

typedef _Float16 f16x8 __attribute__((ext_vector_type(8)));
typedef float    f32x4 __attribute__((ext_vector_type(4)));

#define MFMA(a,b,c) __builtin_amdgcn_mfma_f32_16x16x32_f16(a,b,c,0,0,0)

#define Bb 1024
#define Tt 128
#define NG 32          // groups
#define GB 8           // blocks per group (split-K over H=512 -> 64 cols each)
#define Rr 32          // rows per group (two MFMA M-tiles)
#define NT 512         // threads per block (8 waves)

// packed fragment regions in d_ws (units: halves) -- identical pack to R0
#define W2SG_OFF 0
#define W2SG_HALVES (64*16*2*512)
#define W2MU_OFF (W2SG_OFF + W2SG_HALVES)
#define W2MU_HALVES (4*16*2*512)
#define W1MU_OFF (W2MU_OFF + W2MU_HALVES)
#define W1_HALVES (32*3*2*512)
#define W1SG_OFF (W1MU_OFF + W1_HALVES)
#define WS_HALVES (W1SG_OFF + W1_HALVES)
#define ACC_BYTES_OFF ((size_t)WS_HALVES * 2)
#define ACC_FLOATS (3 * NG * Rr * 64)     // 3 slots x 32 groups x 32x64
#define CNT_BYTES_OFF (ACC_BYTES_OFF + (size_t)ACC_FLOATS * 4)
#define CNT_STRIDE 16                     // pad counters to 64 B

__global__ __launch_bounds__(256) void pack_weights(
    const float* __restrict__ W1_mu, const float* __restrict__ W2_mu,
    const float* __restrict__ W1_sg, const float* __restrict__ W2_sg,
    _Float16* __restrict__ wsh)
{
    int gid = blockIdx.x * 256 + threadIdx.x;
    if (gid >= 81920) return;
    const float* src; int ncols, kvalid; size_t dst;
    int id, tile, ks, lane;
    if (gid < 65536) {                 // W2_sg: 64 tiles x 16 ks x 64 lanes
        id = gid; tile = id >> 10; id &= 1023; ks = id >> 6; lane = id & 63;
        src = W2_sg; ncols = 1024; kvalid = 512;
        dst = W2SG_OFF + (size_t)((tile*16 + ks)*2) * 512 + lane*8;
    } else if (gid < 69632) {          // W2_mu: 4 x 16 x 64
        id = gid - 65536; tile = id >> 10; id &= 1023; ks = id >> 6; lane = id & 63;
        src = W2_mu; ncols = 64; kvalid = 512;
        dst = W2MU_OFF + (size_t)((tile*16 + ks)*2) * 512 + lane*8;
    } else if (gid < 75776) {          // W1_mu: 32 tiles x 3 ks x 64
        id = gid - 69632; tile = id / 192; id %= 192; ks = id >> 6; lane = id & 63;
        src = W1_mu; ncols = 512; kvalid = 80;
        dst = W1MU_OFF + (size_t)((tile*3 + ks)*2) * 512 + lane*8;
    } else {                           // W1_sg
        id = gid - 75776; tile = id / 192; id %= 192; ks = id >> 6; lane = id & 63;
        src = W1_sg; ncols = 512; kvalid = 80;
        dst = W1SG_OFF + (size_t)((tile*3 + ks)*2) * 512 + lane*8;
    }
    const int n  = tile*16 + (lane & 15);
    const int kb = ks*32 + ((lane >> 4) << 3);
    f16x8 hi8, lo8;
    #pragma unroll
    for (int jj = 0; jj < 8; ++jj) {
        int k = kb + jj;
        float wv = (k < kvalid) ? src[(size_t)k * ncols + n] : 0.f;
        _Float16 h = (_Float16)wv;
        hi8[jj] = h;
        lo8[jj] = (_Float16)(wv - (float)h);
    }
    *((f16x8*)(wsh + dst))       = hi8;
    *((f16x8*)(wsh + dst + 512)) = lo8;
}

__global__ __launch_bounds__(NT, 2) void nsde_r3(
    const float* __restrict__ y0, const float* __restrict__ controls,
    const float* __restrict__ noise,
    const float* __restrict__ b1_mu, const float* __restrict__ b2_mu,
    const float* __restrict__ b1_sg, const float* __restrict__ b2_sg,
    const _Float16* __restrict__ wf,
    float* __restrict__ accbuf, unsigned int* __restrict__ cnt,
    float* __restrict__ out)
{
    __shared__ _Float16 s_xhi[Rr][104], s_xlo[Rr][104];     // x, K=96 (+pad)
    __shared__ _Float16 s_hhi[2][Rr][72], s_hlo[2][Rr][72]; // h slices (64+pad)
    __shared__ float s_y[Rr*64];     // [r*64+n]
    __shared__ float s_dw[Rr][16];
    __shared__ float s_part[Rr*64];  // sg partial (dW-folded)
    __shared__ float s_pmu[Rr*64];   // mu partial (*dt)

    const int tid  = threadIdx.x;
    const int lane = tid & 63, w = tid >> 6;
    const int m15  = lane & 15, quad = lane >> 4;
    const int j    = blockIdx.x & 7;        // K-slice id
    const int g    = blockIdx.x >> 3;       // group
    const int r0   = g * Rr;

    // per-wave constants
    const int l  = w >> 2;                  // GEMM1 layer: 0=mu 1=sg
    const int ct = w & 3;                   // GEMM1 col-tile within slice
    const int tg = j*4 + ct;                // global W1 H-tile
    const float bias1 = (l ? b1_sg : b1_mu)[j*64 + ct*16 + m15];
    float b2v[8];
    #pragma unroll
    for (int t = 0; t < 8; ++t)
        b2v[t] = (j == 0) ? b2_sg[(w + t*8)*16 + m15] : 0.f;
    const float b2m = (w < 4 && j == 0) ? b2_mu[w*16 + m15] * 0.01f : 0.f;

    // ---- small weights register-resident (40 VGPRs): W1 slice + W2_mu tile
    f16x8 w1h[3], w1l[3];
    {
        const _Float16* w1base = wf + (l ? W1SG_OFF : W1MU_OFF);
        #pragma unroll
        for (int ks = 0; ks < 3; ++ks) {
            const _Float16* bp = w1base + (size_t)((tg*3 + ks)*2)*512 + lane*8;
            w1h[ks] = *(const f16x8*)bp;
            w1l[ks] = *(const f16x8*)(bp + 512);
        }
    }
    f16x8 wmu[4];
    {
        const int wm = w & 3;   // waves >=4 load a valid (unused) tile
        const _Float16* bp = wf + W2MU_OFF
            + (size_t)((wm*16 + 2*j)*2)*512 + lane*8;
        wmu[0] = *(const f16x8*)(bp);
        wmu[1] = *(const f16x8*)(bp + 512);
        wmu[2] = *(const f16x8*)(bp + 1024);
        wmu[3] = *(const f16x8*)(bp + 1536);
    }

    // ---- init
    for (int e = tid; e < Rr*24; e += NT) {   // zero x K-pad cols 80..103
        int r = e / 24, c = 80 + e % 24;
        s_xhi[r][c] = (_Float16)0.f; s_xlo[r][c] = (_Float16)0.f;
    }
    {
        const int e0 = tid*4, r = e0 >> 6, n = e0 & 63;
        float4 yv = *(const float4*)&y0[(size_t)(r0 + r)*64 + n];
        float vv[4] = {yv.x, yv.y, yv.z, yv.w};
        #pragma unroll
        for (int q = 0; q < 4; ++q) {
            s_y[e0+q] = vv[q];
            _Float16 h = (_Float16)vv[q];
            s_xhi[r][n+q] = h; s_xlo[r][n+q] = (_Float16)(vv[q] - (float)h);
        }
        if ((tid >> 6) == j)                  // wave j -> block's 1/8 row chunk
            *(float4*)&out[(size_t)(r0 + r)*64 + n] = yv;
        const int r2 = tid >> 4, c2 = tid & 15;
        float u = controls[c2];
        _Float16 h = (_Float16)u;
        s_xhi[r2][64+c2] = h; s_xlo[r2][64+c2] = (_Float16)(u - (float)h);
        s_dw[r2][c2] = noise[(size_t)(r0 + r2)*16 + c2] * 0.1f;
    }
    __syncthreads();

    for (int k = 0; k < Tt-1; ++k) {
        // ======== GEMM1: per wave one 16-col H-tile, both M-tiles
        #pragma unroll
        for (int mt = 0; mt < 2; ++mt) {
            f32x4 a0 = {0,0,0,0}, a1 = {0,0,0,0}, a2 = {0,0,0,0};
            #pragma unroll
            for (int ks = 0; ks < 3; ++ks) {
                f16x8 ah = *(const f16x8*)&s_xhi[mt*16 + m15][ks*32 + quad*8];
                f16x8 al = *(const f16x8*)&s_xlo[mt*16 + m15][ks*32 + quad*8];
                a0 = MFMA(ah, w1h[ks], a0);
                a1 = MFMA(ah, w1l[ks], a1);
                a2 = MFMA(al, w1h[ks], a2);
            }
            f32x4 s = a0 + a1 + a2;
            #pragma unroll
            for (int rg = 0; rg < 4; ++rg) {
                int row = mt*16 + quad*4 + rg;
                float v = fmaxf(s[rg] + bias1, 0.f);
                _Float16 h = (_Float16)v;
                s_hhi[l][row][ct*16 + m15] = h;
                s_hlo[l][row][ct*16 + m15] = (_Float16)(v - (float)h);
            }
        }
        // prefetch next-step controls/noise into regs (hidden under GEMM2)
        float u_nx = 0.f, dw_nx = 0.f;
        const int r2 = tid >> 4, c2 = tid & 15;
        if (k < Tt-2) {
            u_nx  = controls[(size_t)(k+1)*16 + c2];
            dw_nx = noise[((size_t)(k+1)*Bb + r0 + r2)*16 + c2] * 0.1f;
        }
        __syncthreads();

        // ======== GEMM2 over this block's K-slice (local k in [0,64))
        float dwv[2][4];
        #pragma unroll
        for (int mt = 0; mt < 2; ++mt)
            #pragma unroll
            for (int rg = 0; rg < 4; ++rg)
                dwv[mt][rg] = s_dw[mt*16 + quad*4 + rg][m15];

        // -- mu partial (waves 0..3 take n-tile w), wmu register-resident
        if (w < 4) {
            #pragma unroll
            for (int mt = 0; mt < 2; ++mt) {
                const int rb = mt*16;
                f16x8 Mh0 = *(const f16x8*)&s_hhi[0][rb + m15][quad*8];
                f16x8 Ml0 = *(const f16x8*)&s_hlo[0][rb + m15][quad*8];
                f16x8 Mh1 = *(const f16x8*)&s_hhi[0][rb + m15][32 + quad*8];
                f16x8 Ml1 = *(const f16x8*)&s_hlo[0][rb + m15][32 + quad*8];
                f32x4 hh = {0,0,0,0}, hl = {0,0,0,0}, lh = {0,0,0,0};
                hh = MFMA(Mh0, wmu[0], hh); hl = MFMA(Mh0, wmu[1], hl);
                lh = MFMA(Ml0, wmu[0], lh);
                hh = MFMA(Mh1, wmu[2], hh); hl = MFMA(Mh1, wmu[3], hl);
                lh = MFMA(Ml1, wmu[2], lh);
                f32x4 s = hh + hl + lh;
                #pragma unroll
                for (int rg = 0; rg < 4; ++rg)
                    s_pmu[(rb + quad*4 + rg)*64 + w*16 + m15] = s[rg]*0.01f + b2m;
            }
        }

        // -- sg partials: 8 n-tiles per wave, weights STREAMED (used 2x each).
        // A-fragments for both M-tiles hoisted into registers (32 VGPRs).
        f16x8 Ah[2][2], Al[2][2];   // [mt][half]
        #pragma unroll
        for (int mt = 0; mt < 2; ++mt) {
            Ah[mt][0] = *(const f16x8*)&s_hhi[1][mt*16 + m15][quad*8];
            Al[mt][0] = *(const f16x8*)&s_hlo[1][mt*16 + m15][quad*8];
            Ah[mt][1] = *(const f16x8*)&s_hhi[1][mt*16 + m15][32 + quad*8];
            Al[mt][1] = *(const f16x8*)&s_hlo[1][mt*16 + m15][32 + quad*8];
        }
        // opaque zero: makes sg weight addresses k-dependent -> no LICM,
        // loads stay transient (R1's 128-VGPR pin + spill cannot recur)
        int kz;
        asm volatile("v_mov_b32 %0, 0" : "=v"(kz));
        const _Float16* wsg_base = wf + W2SG_OFF + kz;
        #pragma unroll 2
        for (int t = 0; t < 8; ++t) {
            const int nt = w + t*8;
            const _Float16* bp = wsg_base + (size_t)((nt*16 + 2*j)*2)*512 + lane*8;
            f16x8 bh0 = *(const f16x8*)(bp);
            f16x8 bl0 = *(const f16x8*)(bp + 512);
            f16x8 bh1 = *(const f16x8*)(bp + 1024);
            f16x8 bl1 = *(const f16x8*)(bp + 1536);
            #pragma unroll
            for (int mt = 0; mt < 2; ++mt) {
                f32x4 hh = {0,0,0,0}, hl = {0,0,0,0}, lh = {0,0,0,0};
                hh = MFMA(Ah[mt][0], bh0, hh); hl = MFMA(Ah[mt][0], bl0, hl);
                lh = MFMA(Al[mt][0], bh0, lh);
                hh = MFMA(Ah[mt][1], bh1, hh); hl = MFMA(Ah[mt][1], bl1, hl);
                lh = MFMA(Al[mt][1], bh1, lh);
                f32x4 s = hh + hl + lh;
                #pragma unroll
                for (int rg = 0; rg < 4; ++rg) {
                    float v = (s[rg] + b2v[t]) * dwv[mt][rg];
                    v += __shfl_xor(v, 1); v += __shfl_xor(v, 2);
                    v += __shfl_xor(v, 4); v += __shfl_xor(v, 8);
                    if (m15 == 0) s_part[(mt*16 + quad*4 + rg)*64 + nt] = v;
                }
            }
        }
        __syncthreads();

        // ======== exchange: atomicAdd partials into slot k%3 (validated)
        const int slot = k % 3;
        float* ab = accbuf + ((size_t)slot*NG + g)*(Rr*64);
        const int e0 = tid*4;
        #pragma unroll
        for (int q = 0; q < 4; ++q) {
            float v = s_part[e0+q] + s_pmu[e0+q];
            __hip_atomic_fetch_add(&ab[e0+q], v, __ATOMIC_RELAXED,
                                   __HIP_MEMORY_SCOPE_AGENT);
        }
        __syncthreads();   // drains vmcnt: all adds complete
        if (tid == 0) {
            __hip_atomic_fetch_add(&cnt[g*CNT_STRIDE], 1u, __ATOMIC_RELEASE,
                                   __HIP_MEMORY_SCOPE_AGENT);
            while (__hip_atomic_load(&cnt[g*CNT_STRIDE], __ATOMIC_RELAXED,
                                     __HIP_MEMORY_SCOPE_AGENT) < (unsigned)GB*(k+1))
                __builtin_amdgcn_s_sleep(2);
        }
        __syncthreads();

        // ======== read sum, y update, out write, next x/dW build
        {
            const int r = e0 >> 6, n = e0 & 63;
            float yn[4];
            #pragma unroll
            for (int q = 0; q < 4; ++q) {
                float sum = __hip_atomic_load(&ab[e0+q], __ATOMIC_RELAXED,
                                              __HIP_MEMORY_SCOPE_AGENT);
                yn[q] = s_y[e0+q] + sum;
                s_y[e0+q] = yn[q];
                _Float16 h = (_Float16)yn[q];
                s_xhi[r][n+q] = h;
                s_xlo[r][n+q] = (_Float16)(yn[q] - (float)h);
            }
            if ((tid >> 6) == j) {   // wave j writes this block's 256-elem chunk
                float4 o = {yn[0], yn[1], yn[2], yn[3]};
                *(float4*)&out[((size_t)(k+1)*Bb + r0 + r)*64 + n] = o;
                if (k >= 1) {        // zero slot (k-1)%3 (3-slot rotation safe)
                    float* zb = accbuf + ((size_t)((k-1)%3)*NG + g)*(Rr*64);
                    #pragma unroll
                    for (int q = 0; q < 4; ++q)
                        __hip_atomic_store(&zb[e0+q], 0.f, __ATOMIC_RELAXED,
                                           __HIP_MEMORY_SCOPE_AGENT);
                }
            }
        }
        if (k < Tt-2) {
            _Float16 h = (_Float16)u_nx;
            s_xhi[r2][64+c2] = h; s_xlo[r2][64+c2] = (_Float16)(u_nx - (float)h);
            s_dw[r2][c2] = dw_nx;
        }
        __syncthreads();
    }
}

extern "C" void kernel_launch(void* const* d_in, const int* in_sizes, int n_in,
                              void* d_out, int out_size, void* d_ws, size_t ws_size,
                              hipStream_t stream) {
    const float* y0       = (const float*)d_in[0];
    const float* controls = (const float*)d_in[1];
    const float* noise    = (const float*)d_in[2];
    const float* W1_mu    = (const float*)d_in[3];
    const float* b1_mu    = (const float*)d_in[4];
    const float* W2_mu    = (const float*)d_in[5];
    const float* b2_mu    = (const float*)d_in[6];
    const float* W1_sg    = (const float*)d_in[7];
    const float* b1_sg    = (const float*)d_in[8];
    const float* W2_sg    = (const float*)d_in[9];
    const float* b2_sg    = (const float*)d_in[10];
    float* out = (float*)d_out;
    _Float16* wsh = (_Float16*)d_ws;
    float* accbuf = (float*)((char*)d_ws + ACC_BYTES_OFF);
    unsigned int* cnt = (unsigned int*)((char*)d_ws + CNT_BYTES_OFF);

    // zero accumulator slots + padded counters (ws is poisoned 0xAA each call)
    hipMemsetAsync((char*)d_ws + ACC_BYTES_OFF, 0,
                   (size_t)ACC_FLOATS*4 + (size_t)NG*CNT_STRIDE*4, stream);
    pack_weights<<<320, 256, 0, stream>>>(W1_mu, W2_mu, W1_sg, W2_sg, wsh);
    nsde_r3<<<NG*GB, NT, 0, stream>>>(y0, controls, noise,
                                      b1_mu, b2_mu, b1_sg, b2_sg,
                                      (const _Float16*)wsh,
                                      accbuf, cnt, out);
}